// Round 10
// baseline (173.449 us; speedup 1.0000x reference)
//
#include <hip/hip_runtime.h>

#define WW 1280
#define HH 720
#define NB 8
#define NPIX (HH * WW)            // 921600
#define TOTAL (NB * NPIX)         // 7372800

#define FMAX 4.0f                 // |flow| < 4 -> inlier (corners within +/-4)
#define RHALO 4
#define TH 16                     // 720 = 45*16
#define TW 64                     // 1280 = 20*64
#define TPIX (TH * TW)            // 1024
#define TILES_X (WW / TW)         // 20
#define TILES_Y (HH / TH)         // 45
#define TPB (TILES_X * TILES_Y)   // 900
#define NT (NB * TPB)             // 7200 (divisible by 8; NT/8 == TPB -> XCD x owns batch x)
#define WH (TH + 2 * RHALO)       // 24
#define WWIN (TW + 2 * RHALO)     // 72
#define WPOS (WH * WWIN)          // 1728 scalar window positions
#define TB 256                    // threads per block
#define CAPB 4096                 // per-batch outlier capacity (expect ~120)

// ---------------------------------------------------------------------------
// K1: build per-batch outlier lists (valid target but |fx|>=4 or |fy|>=4).
// Entry = {pixel, fx_bits, fy_bits, depth_bits}.
// ---------------------------------------------------------------------------
__global__ void k1_outliers(const float* __restrict__ flow,
                            const float* __restrict__ depth,
                            int* __restrict__ nOut, int4* __restrict__ lists) {
    int i = blockIdx.x * blockDim.x + threadIdx.x;      // one float4 group
    int p4 = i * 4;
    int b = p4 / NPIX;
    int p = p4 - b * NPIX;
    int y = p / WW;
    int x0 = p - y * WW;
    const float* fb = flow + (size_t)b * 2 * NPIX;
    float4 fx4 = *(const float4*)&fb[p];
    float4 fy4 = *(const float4*)&fb[p + NPIX];
    float fxs[4] = {fx4.x, fx4.y, fx4.z, fx4.w};
    float fys[4] = {fy4.x, fy4.y, fy4.z, fy4.w};
#pragma unroll
    for (int j = 0; j < 4; ++j) {
        float fx = fxs[j], fy = fys[j];
        if (fabsf(fx) < FMAX && fabsf(fy) < FMAX) continue;          // inlier
        float x2 = (float)(x0 + j) + fx, y2 = (float)y + fy;
        if (!(x2 >= 0.f && y2 >= 0.f && x2 <= (float)(WW - 1) && y2 <= (float)(HH - 1)))
            continue;                                                 // invalid
        float d = depth[(size_t)b * NPIX + p + j];
        int pos = atomicAdd(&nOut[b], 1);
        if (pos < CAPB)
            lists[b * CAPB + pos] =
                make_int4(p + j, __float_as_int(fx), __float_as_int(fy), __float_as_int(d));
    }
}

// ---------------------------------------------------------------------------
// K2a: MIN pass. Window scan -> LDS atomicMin -> merge outlier mins ->
// write tile's mind to global. Single sweep, NO per-thread arrays (nothing
// can spill). LDS = 4KB.
// ---------------------------------------------------------------------------
__global__ void __launch_bounds__(TB, 4)
k2a_min(const float* __restrict__ flow, const float* __restrict__ depth,
        const int* __restrict__ nOut, const int4* __restrict__ lists,
        int* __restrict__ mindG) {
    __shared__ int mind_t[TPIX];

    int bid = blockIdx.x;
    { const int c = NT >> 3; bid = (bid & 7) * c + (bid >> 3); }  // XCD swizzle
    const int b   = bid / TPB;
    const int tt  = bid - b * TPB;
    const int tty = tt / TILES_X;
    const int ty0 = tty * TH;
    const int tx0 = (tt - tty * TILES_X) * TW;
    const int tid = threadIdx.x;
    const float* flowb  = flow  + (size_t)b * 2 * NPIX;
    const float* depthb = depth + (size_t)b * NPIX;

    {   // init: one int4 per thread (TPIX == TB*4)
        const int IB = __float_as_int(1e30f);
        *(int4*)&mind_t[tid * 4] = make_int4(IB, IB, IB, IB);
    }
    __syncthreads();

    for (int s = tid; s < WPOS; s += TB) {
        int wy = s / WWIN;
        int wx = s - wy * WWIN;
        int gy = ty0 - RHALO + wy;
        int gx = tx0 - RHALO + wx;
        if ((unsigned)gy >= HH || (unsigned)gx >= WW) continue;
        int p = gy * WW + gx;
        float fx = flowb[p];
        float fy = flowb[p + NPIX];
        if (!(fabsf(fx) < FMAX && fabsf(fy) < FMAX)) continue;
        float x2 = (float)gx + fx, y2 = (float)gy + fy;
        if (!(x2 >= 0.f && y2 >= 0.f && x2 <= (float)(WW - 1) && y2 <= (float)(HH - 1)))
            continue;
        float d = depthb[p];
        int db = __float_as_int(d);
        int xL = (int)floorf(x2), yT = (int)floorf(y2);
        int xR = min(xL + 1, WW - 1), yB = min(yT + 1, HH - 1);
        int lxL = xL - tx0, lxR = xR - tx0, lyT = yT - ty0, lyB = yB - ty0;
        if ((unsigned)lyT < TH) {
            if ((unsigned)lxL < TW) atomicMin(&mind_t[lyT * TW + lxL], db);
            if ((unsigned)lxR < TW) atomicMin(&mind_t[lyT * TW + lxR], db);
        }
        if ((unsigned)lyB < TH) {
            if ((unsigned)lxL < TW) atomicMin(&mind_t[lyB * TW + lxL], db);
            if ((unsigned)lxR < TW) atomicMin(&mind_t[lyB * TW + lxR], db);
        }
    }
    // outlier mins
    const int nb = min(nOut[b], CAPB);
    for (int j = tid; j < nb; j += TB) {
        int4 e = lists[b * CAPB + j];
        float fx = __int_as_float(e.y), fy = __int_as_float(e.z);
        int y = e.x / WW, x = e.x - y * WW;
        float x2 = (float)x + fx, y2 = (float)y + fy;
        int xL = min(max((int)floorf(x2), 0), WW - 1);
        int yT = min(max((int)floorf(y2), 0), HH - 1);
        int xR = min(xL + 1, WW - 1), yB = min(yT + 1, HH - 1);
        int lxL = xL - tx0, lxR = xR - tx0, lyT = yT - ty0, lyB = yB - ty0;
        if ((unsigned)lyT < TH) {
            if ((unsigned)lxL < TW) atomicMin(&mind_t[lyT * TW + lxL], e.w);
            if ((unsigned)lxR < TW) atomicMin(&mind_t[lyT * TW + lxR], e.w);
        }
        if ((unsigned)lyB < TH) {
            if ((unsigned)lxL < TW) atomicMin(&mind_t[lyB * TW + lxL], e.w);
            if ((unsigned)lxR < TW) atomicMin(&mind_t[lyB * TW + lxR], e.w);
        }
    }
    __syncthreads();

    {   // write tile's merged min to global (int4 per thread)
        int k4 = tid * 4;
        int ly = k4 >> 6;
        int lx = k4 & 63;
        int4 v = *(int4*)&mind_t[k4];
        *(int4*)&mindG[b * NPIX + (ty0 + ly) * WW + (tx0 + lx)] = v;
    }
}

// ---------------------------------------------------------------------------
// K2b: ADD pass. Re-scan window (L3-warm), gate via global mindG reads
// (same-XCD L2 hits), masked LDS adds, divide, store. Single sweep, no
// per-thread arrays. LDS = 12KB.
// ---------------------------------------------------------------------------
__global__ void __launch_bounds__(TB, 4)
k2b_add(const float* __restrict__ flow, const float* __restrict__ depth,
        const int* __restrict__ nOut, const int4* __restrict__ lists,
        const int* __restrict__ mindG, float* __restrict__ out) {
    __shared__ float sx_t[TPIX];
    __shared__ float sy_t[TPIX];
    __shared__ float cn_t[TPIX];

    int bid = blockIdx.x;
    { const int c = NT >> 3; bid = (bid & 7) * c + (bid >> 3); }  // XCD swizzle
    const int b   = bid / TPB;
    const int tt  = bid - b * TPB;
    const int tty = tt / TILES_X;
    const int ty0 = tty * TH;
    const int tx0 = (tt - tty * TILES_X) * TW;
    const int tid = threadIdx.x;
    const float* flowb  = flow  + (size_t)b * 2 * NPIX;
    const float* depthb = depth + (size_t)b * NPIX;
    const int*   mindb  = mindG + b * NPIX;

    {   // init: one float4 per array per thread
        int k4 = tid * 4;
        float4 z = make_float4(0.f, 0.f, 0.f, 0.f);
        *(float4*)&sx_t[k4] = z;
        *(float4*)&sy_t[k4] = z;
        *(float4*)&cn_t[k4] = z;
    }
    __syncthreads();

    for (int s = tid; s < WPOS; s += TB) {
        int wy = s / WWIN;
        int wx = s - wy * WWIN;
        int gy = ty0 - RHALO + wy;
        int gx = tx0 - RHALO + wx;
        if ((unsigned)gy >= HH || (unsigned)gx >= WW) continue;
        int p = gy * WW + gx;
        float fx = flowb[p];
        float fy = flowb[p + NPIX];
        if (!(fabsf(fx) < FMAX && fabsf(fy) < FMAX)) continue;
        float x2 = (float)gx + fx, y2 = (float)gy + fy;
        if (!(x2 >= 0.f && y2 >= 0.f && x2 <= (float)(WW - 1) && y2 <= (float)(HH - 1)))
            continue;
        float d = depthb[p];
        int db = __float_as_int(d);
        int xL = (int)floorf(x2), yT = (int)floorf(y2);
        int xR = min(xL + 1, WW - 1), yB = min(yT + 1, HH - 1);
        // gate reads from global mind (final merged values, L2-resident)
        int v0 = mindb[yT * WW + xL];
        int v1 = mindb[yT * WW + xR];
        int v2 = mindb[yB * WW + xL];
        int v3 = mindb[yB * WW + xR];
        int lxL = xL - tx0, lxR = xR - tx0, lyT = yT - ty0, lyB = yB - ty0;
        bool o0 = (unsigned)lyT < TH && (unsigned)lxL < TW && v0 == db;
        bool o1 = (unsigned)lyT < TH && (unsigned)lxR < TW && v1 == db;
        bool o2 = (unsigned)lyB < TH && (unsigned)lxL < TW && v2 == db;
        bool o3 = (unsigned)lyB < TH && (unsigned)lxR < TW && v3 == db;
        if (o0) { int l = lyT * TW + lxL;
            atomicAdd(&sx_t[l], -fx); atomicAdd(&sy_t[l], -fy); atomicAdd(&cn_t[l], 1.f); }
        if (o1) { int l = lyT * TW + lxR;
            atomicAdd(&sx_t[l], -fx); atomicAdd(&sy_t[l], -fy); atomicAdd(&cn_t[l], 1.f); }
        if (o2) { int l = lyB * TW + lxL;
            atomicAdd(&sx_t[l], -fx); atomicAdd(&sy_t[l], -fy); atomicAdd(&cn_t[l], 1.f); }
        if (o3) { int l = lyB * TW + lxR;
            atomicAdd(&sx_t[l], -fx); atomicAdd(&sy_t[l], -fy); atomicAdd(&cn_t[l], 1.f); }
    }
    // outlier adds (gate via global mind)
    const int nb = min(nOut[b], CAPB);
    for (int j = tid; j < nb; j += TB) {
        int4 e = lists[b * CAPB + j];
        float fx = __int_as_float(e.y), fy = __int_as_float(e.z);
        int y = e.x / WW, x = e.x - y * WW;
        float x2 = (float)x + fx, y2 = (float)y + fy;
        int xL = min(max((int)floorf(x2), 0), WW - 1);
        int yT = min(max((int)floorf(y2), 0), HH - 1);
        int xR = min(xL + 1, WW - 1), yB = min(yT + 1, HH - 1);
        int gs[4] = { yT * WW + xL, yT * WW + xR, yB * WW + xL, yB * WW + xR };
#pragma unroll
        for (int c = 0; c < 4; ++c) {
            int g = gs[c];
            int ly = g / WW - ty0, lx = g - (g / WW) * WW - tx0;
            if ((unsigned)ly < TH && (unsigned)lx < TW && mindb[g] == e.w) {
                int l = ly * TW + lx;
                atomicAdd(&sx_t[l], -fx);
                atomicAdd(&sy_t[l], -fy);
                atomicAdd(&cn_t[l], 1.0f);
            }
        }
    }
    __syncthreads();

    {   // epilogue: divide + float4 store
        int k4 = tid * 4;
        int ly = k4 >> 6;
        int lx = k4 & 63;
        float4 s4 = *(float4*)&sx_t[k4];
        float4 t4 = *(float4*)&sy_t[k4];
        float4 c4 = *(float4*)&cn_t[k4];
        float4 ox, oy;
        ox.x = (c4.x > 0.f) ? s4.x / c4.x : 0.f;  oy.x = (c4.x > 0.f) ? t4.x / c4.x : 0.f;
        ox.y = (c4.y > 0.f) ? s4.y / c4.y : 0.f;  oy.y = (c4.y > 0.f) ? t4.y / c4.y : 0.f;
        ox.z = (c4.z > 0.f) ? s4.z / c4.z : 0.f;  oy.z = (c4.z > 0.f) ? t4.z / c4.z : 0.f;
        ox.w = (c4.w > 0.f) ? s4.w / c4.w : 0.f;  oy.w = (c4.w > 0.f) ? t4.w / c4.w : 0.f;
        size_t o = (size_t)b * 2 * NPIX + (size_t)(ty0 + ly) * WW + (tx0 + lx);
        *(float4*)&out[o]        = ox;
        *(float4*)&out[o + NPIX] = oy;
    }
}

extern "C" void kernel_launch(void* const* d_in, const int* in_sizes, int n_in,
                              void* d_out, int out_size, void* d_ws, size_t ws_size,
                              hipStream_t stream) {
    const float* flow  = (const float*)d_in[0];
    const float* depth = (const float*)d_in[1];
    float* out = (float*)d_out;

    int*  nOut  = (int*)d_ws;                              // 16 ints
    int4* lists = (int4*)((char*)d_ws + 64);               // NB*CAPB entries
    int*  mindG = (int*)((char*)d_ws + 64 + (size_t)NB * CAPB * 16);  // TOTAL ints

    hipMemsetAsync(nOut, 0, 64, stream);
    k1_outliers<<<TOTAL / 4 / 256, 256, 0, stream>>>(flow, depth, nOut, lists);
    k2a_min<<<NT, TB, 0, stream>>>(flow, depth, nOut, lists, mindG);
    k2b_add<<<NT, TB, 0, stream>>>(flow, depth, nOut, lists, mindG, out);
}